// Round 4
// baseline (685.537 us; speedup 1.0000x reference)
//
#include <hip/hip_runtime.h>

#define NN 100000
#define EE 1600000
#define EPSV 1e-5f

// ================= degree histogram (int) =================
__global__ void deg_kernel(const int* __restrict__ dst, int* __restrict__ degi) {
    int e = blockIdx.x * 256 + threadIdx.x;
    if (e < EE) atomicAdd(&degi[dst[e]], 1);
}

__global__ void dinv_kernel(const int* __restrict__ degi, float* __restrict__ dinv) {
    int n = blockIdx.x * 256 + threadIdx.x;
    if (n < NN) dinv[n] = rsqrtf((float)degi[n] + 1.0f);
}

// ================= 2-level exclusive scan over degi -> offsets =================
__global__ void scan1(const int* __restrict__ degi, int* __restrict__ offsets,
                      int* __restrict__ partial) {
    __shared__ int sdata[256];
    int t = threadIdx.x;
    int n = blockIdx.x * 256 + t;
    int v = (n < NN) ? degi[n] : 0;
    sdata[t] = v;
    __syncthreads();
    for (int off = 1; off < 256; off <<= 1) {
        int x = (t >= off) ? sdata[t - off] : 0;
        __syncthreads();
        sdata[t] += x;
        __syncthreads();
    }
    if (n < NN) offsets[n] = sdata[t] - v;  // exclusive
    if (t == 255) partial[blockIdx.x] = sdata[255];
}

__global__ void scan2(int* __restrict__ partial, int* __restrict__ partial_pref, int nparts) {
    __shared__ int sdata[512];
    int t = threadIdx.x;
    int v = (t < nparts) ? partial[t] : 0;
    sdata[t] = v;
    __syncthreads();
    for (int off = 1; off < 512; off <<= 1) {
        int x = (t >= off) ? sdata[t - off] : 0;
        __syncthreads();
        sdata[t] += x;
        __syncthreads();
    }
    if (t < nparts) partial_pref[t] = sdata[t] - v;  // exclusive
}

__global__ void scan3(int* __restrict__ offsets, const int* __restrict__ partial_pref) {
    int n = blockIdx.x * 256 + threadIdx.x;
    if (n < NN) offsets[n] += partial_pref[n >> 8];
}

// ================= CSR fill: counting-sort edges by dst =================
// Packed (src, coef) 8B record -> single scattered store (halves line touches).
// offsets[] doubles as the cursor: after fill, offsets[n] == end; start = end - degi[n].
__global__ void fill_kernel(const int* __restrict__ src, const int* __restrict__ dst,
                            int* __restrict__ offsets, const float* __restrict__ dinv,
                            int2* __restrict__ sorted) {
    int e = blockIdx.x * 256 + threadIdx.x;
    if (e >= EE) return;
    int s = src[e], d = dst[e];
    int idx = atomicAdd(&offsets[d], 1);
    int2 rec;
    rec.x = s;
    rec.y = __float_as_int(dinv[s] * dinv[d]);
    sorted[idx] = rec;
}

// ================= input projection: h = relu(x @ W_in + b_in) =================
__global__ void input_proj(const float* __restrict__ x, const float* __restrict__ Win,
                           const float* __restrict__ bin, float* __restrict__ h) {
    __shared__ float Ws[320];
    __shared__ float bs[64];
    int t = threadIdx.x;
    for (int i = t; i < 320; i += 256) Ws[i] = Win[i];
    if (t < 64) bs[t] = bin[t];
    __syncthreads();
    int n = blockIdx.x * 4 + (t >> 6);
    int c = t & 63;
    if (n >= NN) return;
    float acc = bs[c];
#pragma unroll
    for (int k = 0; k < 5; ++k) acc += x[n * 5 + k] * Ws[k * 64 + c];
    h[n * 64 + c] = fmaxf(acc, 0.f);
}

// ================= hw = BNrelu(in) @ W (64x64), BN fused into load stage ======
// apply_bn==0: in is already activated (layer 0). Otherwise in=agg of prev layer,
// normalized with stats/gamma/beta while staging into LDS.
__global__ __launch_bounds__(256) void gemm64_bn(const float* __restrict__ in,
                                                 const float* __restrict__ stats,
                                                 const float* __restrict__ gamma,
                                                 const float* __restrict__ beta,
                                                 const float* __restrict__ W,
                                                 float* __restrict__ out, int apply_bn) {
    __shared__ __align__(16) float Ws[4096];
    __shared__ float Hs[64 * 65];
    __shared__ float scale[64], shift[64];
    int t = threadIdx.x;
    if (t < 64) {
        if (apply_bn) {
            const float invN = 1.0f / (float)NN;
            float mean = stats[t] * invN;
            float var = stats[64 + t] * invN - mean * mean;
            float rstd = rsqrtf(var + EPSV);
            float sc = gamma[t] * rstd;
            scale[t] = sc;
            shift[t] = beta[t] - mean * sc;
        } else {
            scale[t] = 1.f;
            shift[t] = 0.f;
        }
    }
    for (int i = t; i < 4096; i += 256) Ws[i] = W[i];
    __syncthreads();
    int base = blockIdx.x * 64;
    for (int i = t; i < 4096; i += 256) {
        int r = i >> 6, c = i & 63;
        float v = 0.f;
        if (base + r < NN) {
            v = in[(base + r) * 64 + c];
            if (apply_bn) v = fmaxf(v * scale[c] + shift[c], 0.f);
        }
        Hs[r * 65 + c] = v;
    }
    __syncthreads();
    int c0 = (t & 15) * 4;
    int r0 = (t >> 4) * 4;
    float acc[4][4] = {};
    for (int k = 0; k < 64; ++k) {
        float4 w = *(const float4*)&Ws[k * 64 + c0];
        float hv[4];
#pragma unroll
        for (int j = 0; j < 4; ++j) hv[j] = Hs[(r0 + j) * 65 + k];
#pragma unroll
        for (int j = 0; j < 4; ++j) {
            acc[j][0] += hv[j] * w.x;
            acc[j][1] += hv[j] * w.y;
            acc[j][2] += hv[j] * w.z;
            acc[j][3] += hv[j] * w.w;
        }
    }
#pragma unroll
    for (int j = 0; j < 4; ++j) {
        int n = base + r0 + j;
        if (n < NN) {
            float4 v = make_float4(acc[j][0], acc[j][1], acc[j][2], acc[j][3]);
            *(float4*)&out[n * 64 + c0] = v;
        }
    }
}

// ================= CSR gather aggregation + fused BN stats =================
// agg[n,c] = hw[n,c]*dinv[n]^2 + b[c] + sum_j hw[src_j,c]*coef_j
// grid-stride over nodes; per-thread running sum/sumsq -> one atomic pair per block.
__global__ __launch_bounds__(256) void agg_kernel(const float* __restrict__ hw,
                                                  const int2* __restrict__ sorted,
                                                  const int* __restrict__ offsets,
                                                  const int* __restrict__ degi,
                                                  const float* __restrict__ dinv,
                                                  const float* __restrict__ b,
                                                  float* __restrict__ agg,
                                                  float* __restrict__ stats) {
    int t = threadIdx.x;
    int c = t & 63;
    int w = t >> 6;
    float bc = b[c];
    float bsum = 0.f, bss = 0.f;
    for (int n = blockIdx.x * 4 + w; n < NN; n += gridDim.x * 4) {
        int cnt = degi[n];
        int start = offsets[n] - cnt;  // offsets[] was bumped to 'end' by fill
        float di = dinv[n];
        float acc = hw[n * 64 + c] * (di * di) + bc;
        for (int base = 0; base < cnt; base += 64) {
            int m = min(64, cnt - base);
            int2 rec = make_int2(0, 0);
            if (c < m) rec = sorted[start + base + c];
            int k = 0;
            for (; k + 4 <= m; k += 4) {
                int s0 = __shfl(rec.x, k);
                int s1 = __shfl(rec.x, k + 1);
                int s2 = __shfl(rec.x, k + 2);
                int s3 = __shfl(rec.x, k + 3);
                float c0 = __int_as_float(__shfl(rec.y, k));
                float c1 = __int_as_float(__shfl(rec.y, k + 1));
                float c2 = __int_as_float(__shfl(rec.y, k + 2));
                float c3 = __int_as_float(__shfl(rec.y, k + 3));
                float v0 = hw[s0 * 64 + c];
                float v1 = hw[s1 * 64 + c];
                float v2 = hw[s2 * 64 + c];
                float v3 = hw[s3 * 64 + c];
                acc += v0 * c0;
                acc += v1 * c1;
                acc += v2 * c2;
                acc += v3 * c3;
            }
            for (; k < m; ++k) {
                int s = __shfl(rec.x, k);
                float cf = __int_as_float(__shfl(rec.y, k));
                acc += hw[s * 64 + c] * cf;
            }
        }
        agg[n * 64 + c] = acc;
        bsum += acc;
        bss += acc * acc;
    }
    __shared__ float red[2][4][64];
    red[0][w][c] = bsum;
    red[1][w][c] = bss;
    __syncthreads();
    if (w == 0) {
        float s = red[0][0][c] + red[0][1][c] + red[0][2][c] + red[0][3][c];
        float ss = red[1][0][c] + red[1][1][c] + red[1][2][c] + red[1][3][c];
        atomicAdd(&stats[c], s);
        atomicAdd(&stats[64 + c], ss);
    }
}

// ================= classifier: relu(BN(agg)@W1+b1)@W2 + b2, BN fused =========
__global__ __launch_bounds__(256) void classifier(const float* __restrict__ agg,
                                                  const float* __restrict__ stats,
                                                  const float* __restrict__ gamma,
                                                  const float* __restrict__ beta,
                                                  const float* __restrict__ W1,
                                                  const float* __restrict__ b1,
                                                  const float* __restrict__ W2,
                                                  const float* __restrict__ b2,
                                                  float* __restrict__ out) {
    __shared__ float W1s[2048];
    __shared__ float b1s[32];
    __shared__ float W2s[32];
    __shared__ float scale[64], shift[64];
    int t = threadIdx.x;
    for (int i = t; i < 2048; i += 256) W1s[i] = W1[i];
    if (t < 32) {
        b1s[t] = b1[t];
        W2s[t] = W2[t];
    }
    if (t < 64) {
        const float invN = 1.0f / (float)NN;
        float mean = stats[t] * invN;
        float var = stats[64 + t] * invN - mean * mean;
        float rstd = rsqrtf(var + EPSV);
        float sc = gamma[t] * rstd;
        scale[t] = sc;
        shift[t] = beta[t] - mean * sc;
    }
    __syncthreads();
    int n = blockIdx.x * 256 + t;
    if (n >= NN) return;
    float4 h4[16];
    const float4* hp = (const float4*)(agg + n * 64);
#pragma unroll
    for (int i = 0; i < 16; ++i) h4[i] = hp[i];
    float* hr = (float*)h4;
#pragma unroll
    for (int k = 0; k < 64; ++k) hr[k] = fmaxf(hr[k] * scale[k] + shift[k], 0.f);
    float o = b2[0];
    for (int c = 0; c < 32; ++c) {
        float z = b1s[c];
#pragma unroll
        for (int k = 0; k < 64; ++k) z += hr[k] * W1s[k * 32 + c];
        o += fmaxf(z, 0.f) * W2s[c];
    }
    out[n] = o;
}

extern "C" void kernel_launch(void* const* d_in, const int* in_sizes, int n_in,
                              void* d_out, int out_size, void* d_ws, size_t ws_size,
                              hipStream_t stream) {
    const float* x    = (const float*)d_in[0];
    const int*   ei   = (const int*)d_in[1];
    const float* Win  = (const float*)d_in[2];
    const float* bin  = (const float*)d_in[3];
    const float* cW   = (const float*)d_in[4];
    const float* cb   = (const float*)d_in[5];
    const float* gam  = (const float*)d_in[6];
    const float* bet  = (const float*)d_in[7];
    const float* W1   = (const float*)d_in[8];
    const float* b1   = (const float*)d_in[9];
    const float* W2   = (const float*)d_in[10];
    const float* b2   = (const float*)d_in[11];
    float* out = (float*)d_out;

    // ---- workspace layout ----
    float* h     = (float*)d_ws;          // NN*64  (layer-0 activated input)
    float* hw    = h + NN * 64;           // NN*64
    float* agg   = hw + NN * 64;          // NN*64
    float* dinv  = agg + NN * 64;         // NN
    float* stats = dinv + NN;             // 3*128
    int*  degi        = (int*)(stats + 3 * 128);   // NN
    int*  offsets     = degi + NN;                 // NN
    int2* sorted      = (int2*)(offsets + NN);     // EE int2

    // scan temporaries aliased into agg (unused until layer loop)
    int* partial      = (int*)agg;        // 512
    int* partial_pref = (int*)agg + 512;  // 512

    const int* src = ei;
    const int* dst = ei + EE;

    const int NB = (NN + 255) / 256;  // 391

    hipMemsetAsync(degi, 0, NN * sizeof(int), stream);
    hipMemsetAsync(stats, 0, 3 * 128 * sizeof(float), stream);

    deg_kernel<<<(EE + 255) / 256, 256, 0, stream>>>(dst, degi);
    dinv_kernel<<<NB, 256, 0, stream>>>(degi, dinv);
    scan1<<<NB, 256, 0, stream>>>(degi, offsets, partial);
    scan2<<<1, 512, 0, stream>>>(partial, partial_pref, NB);
    scan3<<<NB, 256, 0, stream>>>(offsets, partial_pref);
    fill_kernel<<<(EE + 255) / 256, 256, 0, stream>>>(src, dst, offsets, dinv, sorted);
    input_proj<<<(NN + 3) / 4, 256, 0, stream>>>(x, Win, bin, h);

    for (int i = 0; i < 3; ++i) {
        const float* gin = (i == 0) ? h : agg;
        const float* gst = stats + (i - 1) * 128;  // only read when i>0
        gemm64_bn<<<(NN + 63) / 64, 256, 0, stream>>>(gin, gst, gam + (i - 1) * 64,
                                                      bet + (i - 1) * 64, cW + i * 4096,
                                                      hw, i > 0 ? 1 : 0);
        agg_kernel<<<2048, 256, 0, stream>>>(hw, sorted, offsets, degi, dinv,
                                             cb + i * 64, agg, stats + i * 128);
    }

    classifier<<<(NN + 255) / 256, 256, 0, stream>>>(agg, stats + 2 * 128, gam + 2 * 64,
                                                     bet + 2 * 64, W1, b1, W2, b2, out);
}

// Round 6
// 638.745 us; speedup vs baseline: 1.0733x; 1.0733x over previous
//
#include <hip/hip_runtime.h>

#define NN 100000
#define EE 1600000
#define EPSV 1e-5f

// fp32 -> bf16 with round-to-nearest-even (no __hip_bfloat16 dependency)
__device__ __forceinline__ unsigned short f2bf(float f) {
    union { float f; unsigned int u; } cv;
    cv.f = f;
    unsigned int u = cv.u;
    u += 0x7FFFu + ((u >> 16) & 1u);
    return (unsigned short)(u >> 16);
}

__device__ __forceinline__ float bf2f(unsigned short u) {
    union { unsigned int i; float f; } cv;
    cv.i = ((unsigned int)u) << 16;
    return cv.f;
}

// ================= degree histogram (int) =================
__global__ void deg_kernel(const int* __restrict__ dst, int* __restrict__ degi) {
    int e = blockIdx.x * 256 + threadIdx.x;
    if (e < EE) atomicAdd(&degi[dst[e]], 1);
}

__global__ void dinv_kernel(const int* __restrict__ degi, float* __restrict__ dinv) {
    int n = blockIdx.x * 256 + threadIdx.x;
    if (n < NN) dinv[n] = rsqrtf((float)degi[n] + 1.0f);
}

// ================= 2-level exclusive scan over degi -> offsets =================
__global__ void scan1(const int* __restrict__ degi, int* __restrict__ offsets,
                      int* __restrict__ partial) {
    __shared__ int sdata[256];
    int t = threadIdx.x;
    int n = blockIdx.x * 256 + t;
    int v = (n < NN) ? degi[n] : 0;
    sdata[t] = v;
    __syncthreads();
    for (int off = 1; off < 256; off <<= 1) {
        int x = (t >= off) ? sdata[t - off] : 0;
        __syncthreads();
        sdata[t] += x;
        __syncthreads();
    }
    if (n < NN) offsets[n] = sdata[t] - v;  // exclusive
    if (t == 255) partial[blockIdx.x] = sdata[255];
}

__global__ void scan2(int* __restrict__ partial, int* __restrict__ partial_pref, int nparts) {
    __shared__ int sdata[512];
    int t = threadIdx.x;
    int v = (t < nparts) ? partial[t] : 0;
    sdata[t] = v;
    __syncthreads();
    for (int off = 1; off < 512; off <<= 1) {
        int x = (t >= off) ? sdata[t - off] : 0;
        __syncthreads();
        sdata[t] += x;
        __syncthreads();
    }
    if (t < nparts) partial_pref[t] = sdata[t] - v;  // exclusive
}

__global__ void scan3(int* __restrict__ offsets, const int* __restrict__ partial_pref) {
    int n = blockIdx.x * 256 + threadIdx.x;
    if (n < NN) offsets[n] += partial_pref[n >> 8];
}

// ================= CSR fill: counting-sort edges by dst =================
// offsets[] doubles as cursor: after fill, offsets[n]==end; start = end - degi[n].
__global__ void fill_kernel(const int* __restrict__ src, const int* __restrict__ dst,
                            int* __restrict__ offsets, const float* __restrict__ dinv,
                            int2* __restrict__ sorted) {
    int e = blockIdx.x * 256 + threadIdx.x;
    if (e >= EE) return;
    int s = src[e], d = dst[e];
    int idx = atomicAdd(&offsets[d], 1);
    int2 rec;
    rec.x = s;
    rec.y = __float_as_int(dinv[s] * dinv[d]);
    sorted[idx] = rec;
}

// ================= input projection: h = relu(x @ W_in + b_in) =================
__global__ void input_proj(const float* __restrict__ x, const float* __restrict__ Win,
                           const float* __restrict__ bin, float* __restrict__ h) {
    __shared__ float Ws[320];
    __shared__ float bs[64];
    int t = threadIdx.x;
    for (int i = t; i < 320; i += 256) Ws[i] = Win[i];
    if (t < 64) bs[t] = bin[t];
    __syncthreads();
    int n = blockIdx.x * 4 + (t >> 6);
    int c = t & 63;
    if (n >= NN) return;
    float acc = bs[c];
#pragma unroll
    for (int k = 0; k < 5; ++k) acc += x[n * 5 + k] * Ws[k * 64 + c];
    h[n * 64 + c] = fmaxf(acc, 0.f);
}

// ================= hw(bf16) = BNrelu(in) @ W (64x64), BN fused in load =======
__global__ __launch_bounds__(256) void gemm64_bn(const float* __restrict__ in,
                                                 const float* __restrict__ stats,
                                                 const float* __restrict__ gamma,
                                                 const float* __restrict__ beta,
                                                 const float* __restrict__ W,
                                                 unsigned short* __restrict__ out,
                                                 int apply_bn) {
    __shared__ __align__(16) float Ws[4096];
    __shared__ float Hs[64 * 65];
    __shared__ float scale[64], shift[64];
    int t = threadIdx.x;
    if (t < 64) {
        if (apply_bn) {
            const float invN = 1.0f / (float)NN;
            float mean = stats[t] * invN;
            float var = stats[64 + t] * invN - mean * mean;
            float rstd = rsqrtf(var + EPSV);
            float sc = gamma[t] * rstd;
            scale[t] = sc;
            shift[t] = beta[t] - mean * sc;
        } else {
            scale[t] = 1.f;
            shift[t] = 0.f;
        }
    }
    for (int i = t; i < 4096; i += 256) Ws[i] = W[i];
    __syncthreads();
    int base = blockIdx.x * 64;
    for (int i = t; i < 4096; i += 256) {
        int r = i >> 6, c = i & 63;
        float v = 0.f;
        if (base + r < NN) {
            v = in[(base + r) * 64 + c];
            if (apply_bn) v = fmaxf(v * scale[c] + shift[c], 0.f);
        }
        Hs[r * 65 + c] = v;
    }
    __syncthreads();
    int c0 = (t & 15) * 4;
    int r0 = (t >> 4) * 4;
    float acc[4][4] = {};
    for (int k = 0; k < 64; ++k) {
        float4 w = *(const float4*)&Ws[k * 64 + c0];
        float hv[4];
#pragma unroll
        for (int j = 0; j < 4; ++j) hv[j] = Hs[(r0 + j) * 65 + k];
#pragma unroll
        for (int j = 0; j < 4; ++j) {
            acc[j][0] += hv[j] * w.x;
            acc[j][1] += hv[j] * w.y;
            acc[j][2] += hv[j] * w.z;
            acc[j][3] += hv[j] * w.w;
        }
    }
#pragma unroll
    for (int j = 0; j < 4; ++j) {
        int n = base + r0 + j;
        if (n < NN) {
            ushort4 pk;
            pk.x = f2bf(acc[j][0]);
            pk.y = f2bf(acc[j][1]);
            pk.z = f2bf(acc[j][2]);
            pk.w = f2bf(acc[j][3]);
            *(ushort4*)&out[n * 64 + c0] = pk;
        }
    }
}

// ================= CSR gather aggregation (bf16 rows) + fused BN stats ========
// agg[n,c] = hw[n,c]*dinv[n]^2 + b[c] + sum_j hw[src_j,c]*coef_j
__global__ __launch_bounds__(256) void agg_kernel(const unsigned short* __restrict__ hw,
                                                  const int2* __restrict__ sorted,
                                                  const int* __restrict__ offsets,
                                                  const int* __restrict__ degi,
                                                  const float* __restrict__ dinv,
                                                  const float* __restrict__ b,
                                                  float* __restrict__ agg,
                                                  float* __restrict__ stats) {
    int t = threadIdx.x;
    int c = t & 63;
    int w = t >> 6;
    float bc = b[c];
    float bsum = 0.f, bss = 0.f;
    for (int n = blockIdx.x * 4 + w; n < NN; n += gridDim.x * 4) {
        int cnt = degi[n];
        int start = offsets[n] - cnt;
        float di = dinv[n];
        float acc = bf2f(hw[n * 64 + c]) * (di * di) + bc;
        for (int base = 0; base < cnt; base += 64) {
            int m = min(64, cnt - base);
            int2 rec = make_int2(0, 0);
            if (c < m) rec = sorted[start + base + c];
            int k = 0;
            for (; k + 4 <= m; k += 4) {
                int s0 = __shfl(rec.x, k);
                int s1 = __shfl(rec.x, k + 1);
                int s2 = __shfl(rec.x, k + 2);
                int s3 = __shfl(rec.x, k + 3);
                float c0 = __int_as_float(__shfl(rec.y, k));
                float c1 = __int_as_float(__shfl(rec.y, k + 1));
                float c2 = __int_as_float(__shfl(rec.y, k + 2));
                float c3 = __int_as_float(__shfl(rec.y, k + 3));
                float v0 = bf2f(hw[s0 * 64 + c]);
                float v1 = bf2f(hw[s1 * 64 + c]);
                float v2 = bf2f(hw[s2 * 64 + c]);
                float v3 = bf2f(hw[s3 * 64 + c]);
                acc += v0 * c0;
                acc += v1 * c1;
                acc += v2 * c2;
                acc += v3 * c3;
            }
            for (; k < m; ++k) {
                int s = __shfl(rec.x, k);
                float cf = __int_as_float(__shfl(rec.y, k));
                acc += bf2f(hw[s * 64 + c]) * cf;
            }
        }
        agg[n * 64 + c] = acc;
        bsum += acc;
        bss += acc * acc;
    }
    __shared__ float red[2][4][64];
    red[0][w][c] = bsum;
    red[1][w][c] = bss;
    __syncthreads();
    if (w == 0) {
        float s = red[0][0][c] + red[0][1][c] + red[0][2][c] + red[0][3][c];
        float ss = red[1][0][c] + red[1][1][c] + red[1][2][c] + red[1][3][c];
        atomicAdd(&stats[c], s);
        atomicAdd(&stats[64 + c], ss);
    }
}

// ================= classifier: relu(BN(agg)@W1+b1)@W2 + b2, BN fused =========
__global__ __launch_bounds__(256) void classifier(const float* __restrict__ agg,
                                                  const float* __restrict__ stats,
                                                  const float* __restrict__ gamma,
                                                  const float* __restrict__ beta,
                                                  const float* __restrict__ W1,
                                                  const float* __restrict__ b1,
                                                  const float* __restrict__ W2,
                                                  const float* __restrict__ b2,
                                                  float* __restrict__ out) {
    __shared__ float W1s[2048];
    __shared__ float b1s[32];
    __shared__ float W2s[32];
    __shared__ float scale[64], shift[64];
    int t = threadIdx.x;
    for (int i = t; i < 2048; i += 256) W1s[i] = W1[i];
    if (t < 32) {
        b1s[t] = b1[t];
        W2s[t] = W2[t];
    }
    if (t < 64) {
        const float invN = 1.0f / (float)NN;
        float mean = stats[t] * invN;
        float var = stats[64 + t] * invN - mean * mean;
        float rstd = rsqrtf(var + EPSV);
        float sc = gamma[t] * rstd;
        scale[t] = sc;
        shift[t] = beta[t] - mean * sc;
    }
    __syncthreads();
    int n = blockIdx.x * 256 + t;
    if (n >= NN) return;
    float4 h4[16];
    const float4* hp = (const float4*)(agg + n * 64);
#pragma unroll
    for (int i = 0; i < 16; ++i) h4[i] = hp[i];
    float* hr = (float*)h4;
#pragma unroll
    for (int k = 0; k < 64; ++k) hr[k] = fmaxf(hr[k] * scale[k] + shift[k], 0.f);
    float o = b2[0];
    for (int c = 0; c < 32; ++c) {
        float z = b1s[c];
#pragma unroll
        for (int k = 0; k < 64; ++k) z += hr[k] * W1s[k * 32 + c];
        o += fmaxf(z, 0.f) * W2s[c];
    }
    out[n] = o;
}

extern "C" void kernel_launch(void* const* d_in, const int* in_sizes, int n_in,
                              void* d_out, int out_size, void* d_ws, size_t ws_size,
                              hipStream_t stream) {
    const float* x    = (const float*)d_in[0];
    const int*   ei   = (const int*)d_in[1];
    const float* Win  = (const float*)d_in[2];
    const float* bin  = (const float*)d_in[3];
    const float* cW   = (const float*)d_in[4];
    const float* cb   = (const float*)d_in[5];
    const float* gam  = (const float*)d_in[6];
    const float* bet  = (const float*)d_in[7];
    const float* W1   = (const float*)d_in[8];
    const float* b1   = (const float*)d_in[9];
    const float* W2   = (const float*)d_in[10];
    const float* b2   = (const float*)d_in[11];
    float* out = (float*)d_out;

    // ---- workspace layout ----
    float* h     = (float*)d_ws;                        // NN*64 fp32
    unsigned short* hw = (unsigned short*)(h + NN * 64); // NN*64 bf16 (= NN*32 floats)
    float* agg   = h + NN * 64 + NN * 32;               // NN*64 fp32
    float* dinv  = agg + NN * 64;                       // NN
    float* stats = dinv + NN;                           // 3*128
    int*  degi        = (int*)(stats + 3 * 128);        // NN
    int*  offsets     = degi + NN;                      // NN
    int2* sorted      = (int2*)(offsets + NN);          // EE int2

    // scan temporaries aliased into agg (unused until layer loop)
    int* partial      = (int*)agg;        // 512
    int* partial_pref = (int*)agg + 512;  // 512

    const int* src = ei;
    const int* dst = ei + EE;

    const int NB = (NN + 255) / 256;  // 391

    (void)hipMemsetAsync(degi, 0, NN * sizeof(int), stream);
    (void)hipMemsetAsync(stats, 0, 3 * 128 * sizeof(float), stream);

    deg_kernel<<<(EE + 255) / 256, 256, 0, stream>>>(dst, degi);
    dinv_kernel<<<NB, 256, 0, stream>>>(degi, dinv);
    scan1<<<NB, 256, 0, stream>>>(degi, offsets, partial);
    scan2<<<1, 512, 0, stream>>>(partial, partial_pref, NB);
    scan3<<<NB, 256, 0, stream>>>(offsets, partial_pref);
    fill_kernel<<<(EE + 255) / 256, 256, 0, stream>>>(src, dst, offsets, dinv, sorted);
    input_proj<<<(NN + 3) / 4, 256, 0, stream>>>(x, Win, bin, h);

    for (int i = 0; i < 3; ++i) {
        const float* gin = (i == 0) ? h : agg;
        const float* gst = stats + (i - 1) * 128;  // only read when i>0
        gemm64_bn<<<(NN + 63) / 64, 256, 0, stream>>>(gin, gst, gam + (i - 1) * 64,
                                                      bet + (i - 1) * 64, cW + i * 4096,
                                                      hw, i > 0 ? 1 : 0);
        agg_kernel<<<2048, 256, 0, stream>>>(hw, sorted, offsets, degi, dinv,
                                             cb + i * 64, agg, stats + i * 128);
    }

    classifier<<<(NN + 255) / 256, 256, 0, stream>>>(agg, stats + 2 * 128, gam + 2 * 64,
                                                     bet + 2 * 64, W1, b1, W2, b2, out);
}